// Round 3
// baseline (831.990 us; speedup 1.0000x reference)
//
#include <hip/hip_runtime.h>
#include <hip/hip_bf16.h>

// ---------------------------------------------------------------------------
// Net_15762529976343 — R3: pipelined bf16-MFMA GEMM (double-buffered LDS,
// A-register prefetch, 1 barrier/iter), 3 blocks/CU, vectorized staging,
// fused BN, single memset.
// ---------------------------------------------------------------------------

#define GK 18432
#define GN 200
#define NPAD 256
#define GK8 (GK / 8)   // 2304

typedef __attribute__((ext_vector_type(8))) short bf16x8;
typedef __attribute__((ext_vector_type(4))) float f32x4;
typedef unsigned int u32;
typedef unsigned short u16;

static __device__ __forceinline__ u16 f2bf(float v) {
    __hip_bfloat16 h = __float2bfloat16(v);
    return *(u16*)&h;
}

// ---------------- im2col: in [8,2048,H,H] fp32 -> Bt [NPAD][GK] bf16 -------
__global__ __launch_bounds__(256) void im2col_bf16(
    const float* __restrict__ in, u16* __restrict__ Bt,
    int H, int stride, int pad)
{
    int tid = blockIdx.x * 256 + threadIdx.x;   // NPAD*GK/8 threads
    int n = tid / GK8;
    int k0 = (tid - n * GK8) * 8;
    u16 o[8] = {0, 0, 0, 0, 0, 0, 0, 0};
    if (n < GN) {
        int b = n / 25, pp = n - b * 25;
        int oh = pp / 5, ow = pp - oh * 5;
        int rb = oh * stride - pad, sb = ow * stride - pad;
        const float* inb = in + (size_t)b * 2048 * H * H;
#pragma unroll
        for (int j = 0; j < 8; ++j) {
            int k = k0 + j;
            int c = k / 9; int r9 = k - c * 9;
            int kh = r9 / 3, kw = r9 - kh * 3;
            int r = rb + kh, s = sb + kw;
            float v = 0.f;
            if ((unsigned)r < (unsigned)H && (unsigned)s < (unsigned)H)
                v = inb[(c * H + r) * H + s];
            o[j] = f2bf(v);
        }
    }
    *(uint4*)&Bt[(size_t)tid * 8] = *(const uint4*)o;
}

// ---------------- grid_sample of padded f -> Bt [NPAD][GK] bf16 ------------
__global__ __launch_bounds__(256) void gridsample_bf16(
    const float* __restrict__ f, const float* __restrict__ gridb,
    u16* __restrict__ Bt)
{
    int tid = blockIdx.x * 256 + threadIdx.x;
    int n = tid / GK8;
    int k0 = (tid - n * GK8) * 8;
    u16 o[8] = {0, 0, 0, 0, 0, 0, 0, 0};
    if (n < GN) {
        int b = n / 25, p = n - b * 25;
        const float* gb = gridb + (b * 225 + p * 9) * 2;
#pragma unroll
        for (int j = 0; j < 8; ++j) {
            int k = k0 + j;
            int c = k / 9, q = k - c * 9;
            float px = gb[q * 2], py = gb[q * 2 + 1];
            float x0f = floorf(px), y0f = floorf(py);
            int x0 = (int)x0f, y0 = (int)y0f;
            float wx1 = px - x0f, wx0 = 1.f - wx1;
            float wy1 = py - y0f, wy0 = 1.f - wy1;
            const float* fb = f + ((size_t)b * 2048 + c) * 25;
            // padded 7x7: nonzero only for 1<=x<=5, 1<=y<=5
            auto fetch = [&](int xi, int yi) -> float {
                if (xi < 1 || xi > 5 || yi < 1 || yi > 5) return 0.f;
                return fb[(yi - 1) * 5 + (xi - 1)];
            };
            float v = fetch(x0, y0) * wx0 * wy0
                    + fetch(x0 + 1, y0) * wx1 * wy0
                    + fetch(x0, y0 + 1) * wx0 * wy1
                    + fetch(x0 + 1, y0 + 1) * wx1 * wy1;
            o[j] = f2bf(v);
        }
    }
    *(uint4*)&Bt[(size_t)tid * 8] = *(const uint4*)o;
}

// ---------------- pipelined MFMA GEMM --------------------------------------
// C[M,200] += A_f32[M,GK] * Bt_bf16[n][k]^T ; 128x128 tile, BK=32,
// double-buffered LDS, A-reg prefetch, one barrier per K-step.
__global__ __launch_bounds__(256, 3) void gemm_mfma(
    const float* __restrict__ A, const __hip_bfloat16* __restrict__ Bt,
    float* __restrict__ C, int M, int kchunk)
{
    __shared__ u16 As[2][128 * 40];   // stride 40 shorts (pad)
    __shared__ u16 Bs[2][128 * 32];   // global_load_lds wave-contiguous

    const int tid = threadIdx.x;
    const int bn = blockIdx.x * 128;
    const int bm = blockIdx.y * 128;
    const int kbase = blockIdx.z * kchunk;
    const int iters = kchunk >> 5;

    const int wave = tid >> 6, lane = tid & 63;
    const int wm = (wave & 1) * 64, wn = (wave >> 1) * 64;
    const int lm = lane & 15, lq = lane >> 4;

    // A staging: thread -> (row, 16-elem half-row)
    const int arow = tid >> 1;
    const int akh = (tid & 1) * 16;
    const bool aok = (bm + arow) < M;
    const float* aptr = A + (size_t)(bm + arow) * GK + kbase + akh;

    // B staging: 2 global_load_lds per thread
    const int brow = wave * 32 + (lane >> 2);
    const int bkoff = (lane & 3) * 8;
    const __hip_bfloat16* bptr0 = Bt + (size_t)(bn + brow) * GK + kbase + bkoff;
    const __hip_bfloat16* bptr1 = bptr0 + (size_t)16 * GK;

    f32x4 acc[4][4] = {};

#define PACK_WRITE(buf, r0, r1, r2, r3)                                        \
    {                                                                          \
        uint4* awr = (uint4*)&As[buf][arow * 40 + akh];                        \
        awr[0] = make_uint4(                                                   \
            __builtin_amdgcn_perm(__float_as_uint(r0.y), __float_as_uint(r0.x), 0x07060302u), \
            __builtin_amdgcn_perm(__float_as_uint(r0.w), __float_as_uint(r0.z), 0x07060302u), \
            __builtin_amdgcn_perm(__float_as_uint(r1.y), __float_as_uint(r1.x), 0x07060302u), \
            __builtin_amdgcn_perm(__float_as_uint(r1.w), __float_as_uint(r1.z), 0x07060302u));\
        awr[1] = make_uint4(                                                   \
            __builtin_amdgcn_perm(__float_as_uint(r2.y), __float_as_uint(r2.x), 0x07060302u), \
            __builtin_amdgcn_perm(__float_as_uint(r2.w), __float_as_uint(r2.z), 0x07060302u), \
            __builtin_amdgcn_perm(__float_as_uint(r3.y), __float_as_uint(r3.x), 0x07060302u), \
            __builtin_amdgcn_perm(__float_as_uint(r3.w), __float_as_uint(r3.z), 0x07060302u));\
    }

    // ---- prologue: stage k-step 0 into buffer 0
    __builtin_amdgcn_global_load_lds((const u32*)bptr0, (u32*)&Bs[0][wave * 1024], 16, 0, 0);
    __builtin_amdgcn_global_load_lds((const u32*)bptr1, (u32*)&Bs[0][wave * 1024 + 512], 16, 0, 0);
    {
        float4 a0, a1, a2, a3;
        if (aok) {
            const float4* ap = (const float4*)aptr;
            a0 = ap[0]; a1 = ap[1]; a2 = ap[2]; a3 = ap[3];
        } else {
            a0 = a1 = a2 = a3 = make_float4(0.f, 0.f, 0.f, 0.f);
        }
        PACK_WRITE(0, a0, a1, a2, a3);
    }
    __syncthreads();

    for (int k = 0; k < iters; ++k) {
        const int cur = k & 1, nxt = cur ^ 1;
        const bool more = (k + 1) < iters;
        float4 a0, a1, a2, a3;
        if (more) {
            const int koff = (k + 1) << 5;
            __builtin_amdgcn_global_load_lds((const u32*)(bptr0 + koff),
                                             (u32*)&Bs[nxt][wave * 1024], 16, 0, 0);
            __builtin_amdgcn_global_load_lds((const u32*)(bptr1 + koff),
                                             (u32*)&Bs[nxt][wave * 1024 + 512], 16, 0, 0);
            if (aok) {
                const float4* ap = (const float4*)(aptr + koff);
                a0 = ap[0]; a1 = ap[1]; a2 = ap[2]; a3 = ap[3];
            } else {
                a0 = a1 = a2 = a3 = make_float4(0.f, 0.f, 0.f, 0.f);
            }
        }

        bf16x8 af[4], bfr[4];
#pragma unroll
        for (int i = 0; i < 4; ++i) {
            af[i]  = *(const bf16x8*)&As[cur][(wm + i * 16 + lm) * 40 + lq * 8];
            bfr[i] = *(const bf16x8*)&Bs[cur][(wn + i * 16 + lm) * 32 + lq * 8];
        }
#pragma unroll
        for (int i = 0; i < 4; ++i)
#pragma unroll
            for (int j = 0; j < 4; ++j)
                acc[i][j] = __builtin_amdgcn_mfma_f32_16x16x32_bf16(
                    af[i], bfr[j], acc[i][j], 0, 0, 0);

        if (more) PACK_WRITE(nxt, a0, a1, a2, a3);
        __syncthreads();
    }

#pragma unroll
    for (int i = 0; i < 4; ++i) {
        int row0 = bm + wm + i * 16 + lq * 4;
#pragma unroll
        for (int j = 0; j < 4; ++j) {
            int col = bn + wn + j * 16 + lm;
            if (col < GN) {
#pragma unroll
                for (int r = 0; r < 4; ++r)
                    if (row0 + r < M)
                        atomicAdd(&C[(size_t)(row0 + r) * GN + col], acc[i][j][r]);
            }
        }
    }
#undef PACK_WRITE
}

// -------- fused BN: stats over 200 + apply (+relu), [c][n] -> NCHW ---------
__global__ void bn_fused(const float* __restrict__ y,
                         const float* __restrict__ g,
                         const float* __restrict__ bb,
                         float* __restrict__ out, int relu)
{
    int ch = blockIdx.x;
    int lane = threadIdx.x;   // 64
    const float* p = y + (size_t)ch * GN;
    float s = 0.f, sq = 0.f;
    for (int idx = lane; idx < GN; idx += 64) {
        float v = p[idx];
        s += v; sq += v * v;
    }
    for (int off = 32; off; off >>= 1) {
        s += __shfl_down(s, off);
        sq += __shfl_down(sq, off);
    }
    s = __shfl(s, 0);
    sq = __shfl(sq, 0);
    float m = s * (1.f / 200.f);
    float var = sq * (1.f / 200.f) - m * m;   // ddof=0, matches jnp.var
    float rstd = rsqrtf(var + 1e-5f);
    float sc = rstd * g[ch];
    float sh = bb[ch] - m * sc;
    for (int idx = lane; idx < GN; idx += 64) {
        float v = p[idx] * sc + sh;
        if (relu) v = fmaxf(v, 0.f);
        int b = idx / 25, pp = idx - b * 25;
        out[(size_t)b * 51200 + ch * 25 + pp] = v;
    }
}

// -------- fc2 (relu of hmat folded here) -----------------------------------
__global__ void fc2_kernel(const float* __restrict__ hmat,
                           const float* __restrict__ fc2w,
                           float* __restrict__ pbuf)
{
    int n = blockIdx.x;            // 0..199
    int oo = threadIdx.x >> 6;     // 0..3
    int lane = threadIdx.x & 63;
    float s = 0.f;
#pragma unroll
    for (int j = 0; j < 8; ++j) {
        int hh = lane + 64 * j;
        s += fmaxf(hmat[(size_t)hh * GN + n], 0.f) * fc2w[oo * 512 + hh];
    }
    for (int off = 32; off; off >>= 1) s += __shfl_down(s, off);
    if (lane == 0) pbuf[n * 4 + oo] = s;
}

// -------- theta (d_out) + sampling grid pixel coords -----------------------
__global__ void theta_grids_kernel(const float* __restrict__ pbuf,
                                   float* __restrict__ gridb,
                                   float* __restrict__ outT)
{
    int tid = blockIdx.x * 256 + threadIdx.x;   // 1800
    if (tid >= 1800) return;
    int b = tid / 225;
    int rem = tid % 225;
    int p = rem / 9;
    int k = rem % 9;
    int i = p / 5, j = p % 5;
    int dy = k / 3, dx = k % 3;
    int n = b * 25 + p;
    float p0 = pbuf[n * 4 + 0];
    float p1 = pbuf[n * 4 + 1];
    float p2 = pbuf[n * 4 + 2];
    float p3 = pbuf[n * 4 + 3];
    float x = (float)(j + dx) * (1.f / 3.f) - 1.f;
    float y = (float)(i + dy) * (1.f / 3.f) - 1.f;
    float gx = (1.f + p0) * x + p1;
    float gy = (1.f + p2) * y + p3;
    gridb[tid * 2 + 0] = (gx + 1.f) * 3.f;
    gridb[tid * 2 + 1] = (gy + 1.f) * 3.f;
    if (k == 0) {
        outT[n * 6 + 0] = 1.f + p0;
        outT[n * 6 + 1] = 0.f;
        outT[n * 6 + 2] = p1;
        outT[n * 6 + 3] = 0.f;
        outT[n * 6 + 4] = 1.f + p2;
        outT[n * 6 + 5] = p3;
    }
}

// -------- softmax over 201*25 per batch (+bias) ----------------------------
__global__ void softmax_kernel(const float* __restrict__ stn,
                               const float* __restrict__ bias,
                               float* __restrict__ outC,
                               float* __restrict__ outS)
{
    int b = blockIdx.x;
    __shared__ float red[256];
    int t = threadIdx.x;

    float mx = -1e30f;
    for (int idx = t; idx < 5025; idx += 256) {
        int o = idx / 25, pp = idx % 25;
        mx = fmaxf(mx, stn[(size_t)o * GN + b * 25 + pp] + bias[o]);
    }
    red[t] = mx; __syncthreads();
    for (int s = 128; s; s >>= 1) {
        if (t < s) red[t] = fmaxf(red[t], red[t + s]);
        __syncthreads();
    }
    mx = red[0]; __syncthreads();

    float sm = 0.f;
    for (int idx = t; idx < 5025; idx += 256) {
        int o = idx / 25, pp = idx % 25;
        sm += expf(stn[(size_t)o * GN + b * 25 + pp] + bias[o] - mx);
    }
    red[t] = sm; __syncthreads();
    for (int s = 128; s; s >>= 1) {
        if (t < s) red[t] += red[t + s];
        __syncthreads();
    }
    float inv = 1.f / red[0];

    for (int idx = t; idx < 5025; idx += 256) {
        int o = idx / 25, pp = idx % 25;
        outS[b * 5025 + idx] =
            expf(stn[(size_t)o * GN + b * 25 + pp] + bias[o] - mx) * inv;
    }
    for (int o = t; o < 201; o += 256) {
        float cs = 0.f;
        for (int pp = 0; pp < 25; ++pp)
            cs += expf(stn[(size_t)o * GN + b * 25 + pp] + bias[o] - mx);
        outC[b * 201 + o] = cs * inv;
    }
}

// ---------------------------------------------------------------------------
extern "C" void kernel_launch(void* const* d_in, const int* in_sizes, int n_in,
                              void* d_out, int out_size, void* d_ws, size_t ws_size,
                              hipStream_t stream)
{
    const float* x           = (const float*)d_in[0];
    const float* conv_last_w = (const float*)d_in[3];
    const float* bn_last_g   = (const float*)d_in[4];
    const float* bn_last_b   = (const float*)d_in[5];
    const float* loc_w1      = (const float*)d_in[6];
    const float* loc_g1      = (const float*)d_in[7];
    const float* loc_b1      = (const float*)d_in[8];
    const float* loc_w2      = (const float*)d_in[9];
    const float* loc_g2      = (const float*)d_in[10];
    const float* loc_b2      = (const float*)d_in[11];
    const float* fc1_w       = (const float*)d_in[12];
    const float* fc2_w       = (const float*)d_in[13];
    const float* conv_stn_w  = (const float*)d_in[14];
    const float* conv_stn_b  = (const float*)d_in[15];

    u16* Bt = (u16*)d_ws;                        // NPAD*GK bf16 = 9.44 MB
    float* fp = (float*)((char*)d_ws + (size_t)NPAD * GK * 2);
    // accumulator region (single memset):
    float* t1a  = fp;                        // 409,600
    float* t1b  = t1a + 409600;              // 409,600
    float* t1c  = t1b + 409600;              // 409,600
    float* hmat = t1c + 409600;              // 102,400
    float* stn  = hmat + 102400;             // 40,200
    // non-accumulated scratch:
    float* fbuf  = stn + 40200;              // 409,600
    float* xs1   = fbuf + 409600;            // 409,600
    float* xs    = xs1 + 409600;             // 409,600
    float* pbuf  = xs + 409600;              // 800
    float* gridb = pbuf + 800;               // 3,600

    float* outC = (float*)d_out;             // [8,201]
    float* outS = outC + 8 * 201;            // [8,201,5,5]
    float* outT = outS + 8 * 201 * 25;       // [200,2,3]

    dim3 b256(256);
    const int nB = (NPAD * GK / 8) / 256;    // 2304 blocks

    // one memset for all atomically-accumulated buffers
    hipMemsetAsync(t1a, 0, (size_t)(409600 * 3 + 102400 + 40200) * sizeof(float), stream);

    // conv_last (s2,p1) + bn -> fbuf
    im2col_bf16<<<nB, b256, 0, stream>>>(x, Bt, 10, 2, 1);
    gemm_mfma<<<dim3(2, 16, 24), b256, 0, stream>>>(conv_last_w, (__hip_bfloat16*)Bt, t1a, 2048, GK / 24);
    bn_fused<<<2048, 64, 0, stream>>>(t1a, bn_last_g, bn_last_b, fbuf, 0);

    // loc conv1 + bn + relu -> xs1
    im2col_bf16<<<nB, b256, 0, stream>>>(fbuf, Bt, 5, 1, 1);
    gemm_mfma<<<dim3(2, 16, 24), b256, 0, stream>>>(loc_w1, (__hip_bfloat16*)Bt, t1b, 2048, GK / 24);
    bn_fused<<<2048, 64, 0, stream>>>(t1b, loc_g1, loc_b1, xs1, 1);

    // loc conv2 + bn + relu -> xs
    im2col_bf16<<<nB, b256, 0, stream>>>(xs1, Bt, 5, 1, 1);
    gemm_mfma<<<dim3(2, 16, 24), b256, 0, stream>>>(loc_w2, (__hip_bfloat16*)Bt, t1c, 2048, GK / 24);
    bn_fused<<<2048, 64, 0, stream>>>(t1c, loc_g2, loc_b2, xs, 1);

    // fc1 (patches == im2col(xs)); relu folded into fc2 read
    im2col_bf16<<<nB, b256, 0, stream>>>(xs, Bt, 5, 1, 1);
    gemm_mfma<<<dim3(2, 4, 48), b256, 0, stream>>>(fc1_w, (__hip_bfloat16*)Bt, hmat, 512, GK / 48);

    // fc2 -> p; theta -> d_out; grids
    fc2_kernel<<<200, 256, 0, stream>>>(hmat, fc2_w, pbuf);
    theta_grids_kernel<<<8, 256, 0, stream>>>(pbuf, gridb, outT);

    // grid_sample -> Bt (im2col layout of temp)
    gridsample_bf16<<<nB, b256, 0, stream>>>(fbuf, gridb, Bt);

    // conv_stn (bias folded into softmax)
    gemm_mfma<<<dim3(2, 2, 96), b256, 0, stream>>>(conv_stn_w, (__hip_bfloat16*)Bt, stn, 201, GK / 96);

    // softmax + outputs
    softmax_kernel<<<8, 256, 0, stream>>>(stn, conv_stn_b, outC, outS);
}